// Round 7
// baseline (485.420 us; speedup 1.0000x reference)
//
#include <hip/hip_runtime.h>
#include <hip/hip_cooperative_groups.h>
#include <math.h>

namespace cg = cooperative_groups;

#define N_NODES 50000
#define N_EDGES 800000
#define D_FEAT 64
#define XCHUNKS (N_NODES * D_FEAT / 8)   // 400000 x->bf16 chunks (8 elems each)
#define NVB 3125                         // virtual blocks: 16 rows each (exact)
#define GRID_BLOCKS 2048                 // 8 blocks/CU * 256 CU, co-resident

// ---- bf16 helpers (RNE) ----
__device__ __forceinline__ unsigned short f2bf(float f) {
    unsigned u = __float_as_uint(f);
    u += 0x7FFFu + ((u >> 16) & 1u);
    return (unsigned short)(u >> 16);
}
__device__ __forceinline__ unsigned pack2bf(float lo, float hi) {
    return (unsigned)f2bf(lo) | ((unsigned)f2bf(hi) << 16);
}
__device__ __forceinline__ float bf_lo(unsigned u) { return __uint_as_float(u << 16); }
__device__ __forceinline__ float bf_hi(unsigned u) { return __uint_as_float(u & 0xFFFF0000u); }

// Fast ELU: native v_exp_f32 (abs threshold 0.765 makes expm1 precision moot).
__device__ __forceinline__ float elu_f(float x) {
    return x > 0.f ? x : (__expf(x) - 1.f);
}

// One 8-edge step for one row-group (16 lanes/row, 4 bf16 features per lane).
// Proven 32-VGPR shape from round 6 — unchanged.
template <bool PACKED, bool MASKED>
__device__ __forceinline__ void edge_step8(const char* __restrict__ hb,
                                           const int2* __restrict__ pairs,
                                           const int* __restrict__ cols,
                                           const float* __restrict__ vals,
                                           int e, int e1, int boff,
                                           float4& A, float4& B) {
    int off[8]; float v[8];
    #pragma unroll
    for (int k = 0; k < 8; ++k) {
        const int t = e + k;
        const int idx = MASKED ? (t < e1 ? t : e1 - 1) : t;
        if constexpr (PACKED) {
            const unsigned long long pw =
                __builtin_nontemporal_load((const unsigned long long*)pairs + idx);
            off[k] = (int)(unsigned)(pw & 0xFFFFFFFFull);
            v[k]   = __uint_as_float((unsigned)(pw >> 32));
        } else {
            off[k] = __builtin_nontemporal_load(cols + idx) << 7;
            v[k]   = __builtin_nontemporal_load(vals + idx);
        }
        if (MASKED) v[k] = (t < e1) ? v[k] : 0.f;
    }
    uint2 gg[8];
    #pragma unroll
    for (int k = 0; k < 8; ++k)
        gg[k] = *reinterpret_cast<const uint2*>(hb + (unsigned)(off[k] + boff));
    #pragma unroll
    for (int k = 0; k < 8; ++k) {
        float4& acc = (k & 1) ? B : A;
        const float vk = v[k];
        acc.x = fmaf(vk, bf_lo(gg[k].x), acc.x);
        acc.y = fmaf(vk, bf_hi(gg[k].x), acc.y);
        acc.z = fmaf(vk, bf_lo(gg[k].y), acc.z);
        acc.w = fmaf(vk, bf_hi(gg[k].y), acc.w);
    }
}

// One virtual block (16 rows) of one SpMM layer.
// !FUSE: h_out = bf16 [N_NODES][64].  FUSE: h_out = f32 out = y @ W^T + b.
// Wlds: f32 W, chunk-XOR swizzled (conflict-free float4 reads, no padding).
// ylds2: per-wave y rows as packed bf16 (uniform broadcast reads).
template <bool FUSE, bool PACKED>
__device__ __forceinline__ void layer_vb(
    int vb, int lane, int wave,
    const unsigned short* __restrict__ h_in,
    const int2* __restrict__ pairs,
    const int* __restrict__ cols,
    const float* __restrict__ vals,
    const int* __restrict__ row_ptr,
    float s,
    const float* __restrict__ Wlds,
    uint2* __restrict__ ylds2,
    float bj,
    void* __restrict__ h_out)
{
    const int g = lane >> 4;          // row-group 0..3
    const int f4 = lane & 15;         // 8B feature chunk
    const int boff = f4 * 8;
    const int row = vb * 16 + wave * 4 + g;
    const int e0 = row_ptr[row];
    const int e1 = row_ptr[row + 1];
    const char* hb = (const char*)h_in;

    float4 A = make_float4(0.f, 0.f, 0.f, 0.f);
    float4 B = A;
    int e = e0;
    for (; e + 8 <= e1; e += 8)
        edge_step8<PACKED, false>(hb, pairs, cols, vals, e, e1, boff, A, B);
    if (e < e1)
        edge_step8<PACKED, true>(hb, pairs, cols, vals, e, e1, boff, A, B);

    float4 acc;
    acc.x = elu_f((A.x + B.x) * s);
    acc.y = elu_f((A.y + B.y) * s);
    acc.z = elu_f((A.z + B.z) * s);
    acc.w = elu_f((A.w + B.w) * s);

    if constexpr (!FUSE) {
        uint2 wv;
        wv.x = pack2bf(acc.x, acc.y);
        wv.y = pack2bf(acc.z, acc.w);
        *reinterpret_cast<uint2*>((char*)h_out + (size_t)row * 128 + boff) = wv;
    } else {
        uint2* yw = ylds2 + wave * 64;           // 4 rows * 16 uint2
        yw[g * 16 + f4] = make_uint2(pack2bf(acc.x, acc.y), pack2bf(acc.z, acc.w));
        asm volatile("s_waitcnt lgkmcnt(0)" ::: "memory");  // same-wave ds order

        const int j = lane;
        float o0 = bj, o1 = bj, o2 = bj, o3 = bj;
        #pragma unroll
        for (int c = 0; c < 16; ++c) {
            const float4 wv = *reinterpret_cast<const float4*>(
                Wlds + j * 64 + (((unsigned)(c ^ (j & 15))) << 2));
            const uint2 y0 = yw[0 * 16 + c];
            const uint2 y1 = yw[1 * 16 + c];
            const uint2 y2 = yw[2 * 16 + c];
            const uint2 y3 = yw[3 * 16 + c];
            o0 = fmaf(bf_lo(y0.x), wv.x, o0); o0 = fmaf(bf_hi(y0.x), wv.y, o0);
            o0 = fmaf(bf_lo(y0.y), wv.z, o0); o0 = fmaf(bf_hi(y0.y), wv.w, o0);
            o1 = fmaf(bf_lo(y1.x), wv.x, o1); o1 = fmaf(bf_hi(y1.x), wv.y, o1);
            o1 = fmaf(bf_lo(y1.y), wv.z, o1); o1 = fmaf(bf_hi(y1.y), wv.w, o1);
            o2 = fmaf(bf_lo(y2.x), wv.x, o2); o2 = fmaf(bf_hi(y2.x), wv.y, o2);
            o2 = fmaf(bf_lo(y2.y), wv.z, o2); o2 = fmaf(bf_hi(y2.y), wv.w, o2);
            o3 = fmaf(bf_lo(y3.x), wv.x, o3); o3 = fmaf(bf_hi(y3.x), wv.y, o3);
            o3 = fmaf(bf_lo(y3.y), wv.z, o3); o3 = fmaf(bf_hi(y3.y), wv.w, o3);
        }
        float* outp = (float*)h_out;
        const size_t rbase = (size_t)(vb * 16 + wave * 4) * D_FEAT;
        outp[rbase + 0 * D_FEAT + j] = o0;
        outp[rbase + 1 * D_FEAT + j] = o1;
        outp[rbase + 2 * D_FEAT + j] = o2;
        outp[rbase + 3 * D_FEAT + j] = o3;
    }
}

// Stage W into LDS with chunk-XOR swizzle: element (j,d) at
// j*64 + ((d>>2)^(j&15))*4 + (d&3). float4 read back at chunk c is conflict-free.
__device__ __forceinline__ void stage_W(const float* __restrict__ W, float* Wlds, int tid) {
    for (int i = tid; i < 64 * 64; i += 256) {
        const int j = i >> 6, d = i & 63;
        Wlds[j * 64 + ((((unsigned)(d >> 2)) ^ (j & 15)) << 2) + (d & 3)] = W[i];
    }
}

// ---- Cooperative mono-kernel: prep -> sync -> layer0 -> sync -> layer1+proj ----
template <bool PACKED>
__global__ __launch_bounds__(256, 8) void gcn_all(
    const float* __restrict__ x, const int* __restrict__ rows,
    const int* __restrict__ cols, const float* __restrict__ vals,
    const float* __restrict__ scalars, const float* __restrict__ W,
    const float* __restrict__ bvec, float* __restrict__ out,
    int* __restrict__ row_ptr, int2* __restrict__ pairs,
    unsigned short* __restrict__ xbf, unsigned short* __restrict__ h1)
{
    __shared__ float Wlds[64 * 64];      // 16384 B
    __shared__ uint2 ylds2[4 * 64];      //  2048 B  (18432 B total, 8 blocks/CU fits)

    cg::grid_group grid = cg::this_grid();
    const int tid  = threadIdx.x;
    const int lane = tid & 63;
    const int wave = tid >> 6;
    const unsigned gtid = blockIdx.x * 256u + (unsigned)tid;
    const unsigned gsz  = gridDim.x * 256u;

    // ---- phase 0: prep (pack pairs, x->bf16, row_ptr binary search) ----
    if constexpr (PACKED) {
        for (unsigned i = gtid; i < N_EDGES; i += gsz)
            pairs[i] = make_int2(cols[i] << 7, __float_as_int(vals[i]));
    }
    for (unsigned i = gtid; i < XCHUNKS; i += gsz) {
        const float4 f0 = *reinterpret_cast<const float4*>(x + (size_t)i * 8);
        const float4 f1 = *reinterpret_cast<const float4*>(x + (size_t)i * 8 + 4);
        uint4 w4;
        w4.x = pack2bf(f0.x, f0.y); w4.y = pack2bf(f0.z, f0.w);
        w4.z = pack2bf(f1.x, f1.y); w4.w = pack2bf(f1.z, f1.w);
        *reinterpret_cast<uint4*>(xbf + (size_t)i * 8) = w4;
    }
    for (unsigned r = gtid; r <= N_NODES; r += gsz) {
        int lo = 0, hi = N_EDGES;
        while (lo < hi) {
            int mid = (lo + hi) >> 1;
            if (rows[mid] < (int)r) lo = mid + 1; else hi = mid;
        }
        row_ptr[r] = lo;
    }
    grid.sync();

    // ---- phase 1: layer 0 (x_bf -> h1 bf16) ----
    const float s0 = scalars[0];
    for (int vb = blockIdx.x; vb < NVB; vb += gridDim.x)
        layer_vb<false, PACKED>(vb, lane, wave, xbf, pairs, cols, vals, row_ptr,
                                s0, nullptr, nullptr, 0.f, h1);
    grid.sync();

    // ---- phase 2: layer 1 + fused projection (h1 -> out f32) ----
    stage_W(W, Wlds, tid);
    __syncthreads();
    const float s1 = scalars[1];
    const float bj = bvec[lane];
    for (int vb = blockIdx.x; vb < NVB; vb += gridDim.x)
        layer_vb<true, PACKED>(vb, lane, wave, h1, pairs, cols, vals, row_ptr,
                               s1, Wlds, ylds2, bj, out);
}

// ---- Fallback path (round-6 proven 3-kernel pipeline) ----
__global__ __launch_bounds__(256) void prep_kernel(const int* __restrict__ rows,
                                                   const int* __restrict__ cols,
                                                   const float* __restrict__ vals,
                                                   const float* __restrict__ x,
                                                   int* __restrict__ row_ptr,
                                                   int2* __restrict__ pairs,
                                                   unsigned short* __restrict__ xbf,
                                                   int do_pack) {
    const int i = blockIdx.x * blockDim.x + threadIdx.x;
    if (i <= N_NODES) {
        int lo = 0, hi = N_EDGES;
        while (lo < hi) {
            int mid = (lo + hi) >> 1;
            if (rows[mid] < i) lo = mid + 1; else hi = mid;
        }
        row_ptr[i] = lo;
    }
    if (do_pack && i < N_EDGES)
        pairs[i] = make_int2(cols[i] << 7, __float_as_int(vals[i]));
    if (i < XCHUNKS) {
        const float4 f0 = *reinterpret_cast<const float4*>(x + (size_t)i * 8);
        const float4 f1 = *reinterpret_cast<const float4*>(x + (size_t)i * 8 + 4);
        uint4 w4;
        w4.x = pack2bf(f0.x, f0.y); w4.y = pack2bf(f0.z, f0.w);
        w4.z = pack2bf(f1.x, f1.y); w4.w = pack2bf(f1.z, f1.w);
        *reinterpret_cast<uint4*>(xbf + (size_t)i * 8) = w4;
    }
}

template <bool FUSE, bool PACKED>
__global__ __launch_bounds__(256) void gcn_layer_k(
    const unsigned short* __restrict__ h_in,
    const int2* __restrict__ pairs,
    const int* __restrict__ cols,
    const float* __restrict__ vals,
    const int* __restrict__ row_ptr,
    const float* __restrict__ scalar_p,
    const float* __restrict__ W,
    const float* __restrict__ bvec,
    void* __restrict__ h_out)
{
    __shared__ float Wlds[FUSE ? 64 * 64 : 1];
    __shared__ uint2 ylds2[FUSE ? 4 * 64 : 1];
    const int tid = threadIdx.x, lane = tid & 63, wave = tid >> 6;
    float bj = 0.f;
    if constexpr (FUSE) {
        stage_W(W, Wlds, tid);
        bj = bvec[lane];
        __syncthreads();
    }
    layer_vb<FUSE, PACKED>(blockIdx.x, lane, wave, h_in, pairs, cols, vals,
                           row_ptr, scalar_p[0], Wlds, ylds2, bj, h_out);
}

extern "C" void kernel_launch(void* const* d_in, const int* in_sizes, int n_in,
                              void* d_out, int out_size, void* d_ws, size_t ws_size,
                              hipStream_t stream) {
    const float* x       = (const float*)d_in[0];
    const int*   rows    = (const int*)  d_in[1];
    const int*   cols    = (const int*)  d_in[2];
    const float* vals    = (const float*)d_in[3];
    const float* scalars = (const float*)d_in[4];
    const float* W       = (const float*)d_in[5];
    const float* b       = (const float*)d_in[6];
    float* out = (float*)d_out;

    // ws layout: row_ptr | xbf (bf16) | h1 (bf16) | (optional) packed pairs
    const size_t rp_b = (sizeof(int) * (N_NODES + 1) + 255) & ~size_t(255);
    const size_t xb_b = ((size_t)N_NODES * D_FEAT * 2 + 255) & ~size_t(255);
    const size_t pr_b = sizeof(int2) * (size_t)N_EDGES;

    int*            row_ptr = (int*)d_ws;
    unsigned short* xbf     = (unsigned short*)((char*)d_ws + rp_b);
    unsigned short* h1      = (unsigned short*)((char*)d_ws + rp_b + xb_b);
    const bool packed = ws_size >= rp_b + 2 * xb_b + pr_b;
    int2* pairs = packed ? (int2*)((char*)d_ws + rp_b + 2 * xb_b) : nullptr;

    hipError_t err;
    if (packed) {
        void* args[] = {(void*)&x, (void*)&rows, (void*)&cols, (void*)&vals,
                        (void*)&scalars, (void*)&W, (void*)&b, (void*)&out,
                        (void*)&row_ptr, (void*)&pairs, (void*)&xbf, (void*)&h1};
        err = hipLaunchCooperativeKernel(reinterpret_cast<const void*>(&gcn_all<true>),
                                         dim3(GRID_BLOCKS), dim3(256), args, 0, stream);
    } else {
        void* args[] = {(void*)&x, (void*)&rows, (void*)&cols, (void*)&vals,
                        (void*)&scalars, (void*)&W, (void*)&b, (void*)&out,
                        (void*)&row_ptr, (void*)&pairs, (void*)&xbf, (void*)&h1};
        err = hipLaunchCooperativeKernel(reinterpret_cast<const void*>(&gcn_all<false>),
                                         dim3(GRID_BLOCKS), dim3(256), args, 0, stream);
    }

    if (err != hipSuccess) {
        // Fallback: proven 3-kernel pipeline (round 6).
        prep_kernel<<<(N_EDGES + 255) / 256, 256, 0, stream>>>(
            rows, cols, vals, x, row_ptr, pairs, xbf, packed ? 1 : 0);
        if (packed) {
            gcn_layer_k<false, true><<<NVB, 256, 0, stream>>>(
                xbf, pairs, cols, vals, row_ptr, scalars + 0, nullptr, nullptr, h1);
            gcn_layer_k<true, true><<<NVB, 256, 0, stream>>>(
                h1, pairs, cols, vals, row_ptr, scalars + 1, W, b, out);
        } else {
            gcn_layer_k<false, false><<<NVB, 256, 0, stream>>>(
                xbf, nullptr, cols, vals, row_ptr, scalars + 0, nullptr, nullptr, h1);
            gcn_layer_k<true, false><<<NVB, 256, 0, stream>>>(
                h1, nullptr, cols, vals, row_ptr, scalars + 1, W, b, out);
        }
    }
}

// Round 8
// 58.324 us; speedup vs baseline: 8.3228x; 8.3228x over previous
//
#include <hip/hip_runtime.h>
#include <hip/hip_fp16.h>
#include <math.h>

#define N_NODES 50000
#define N_EDGES 800000
#define D_FEAT 64
#define XCHUNKS (N_NODES * D_FEAT / 8)   // 400000 x->f16 chunks (8 elems each)
#define NBLK 3125                        // 16 rows/block * 3125 = 50000 exactly

// ---- f16 helpers ----
__device__ __forceinline__ unsigned pack2h(float a, float b) {
    __half2 h = __floats2half2_rn(a, b);
    return *reinterpret_cast<unsigned*>(&h);
}
__device__ __forceinline__ __half2 as_h2(unsigned u) {
    return *reinterpret_cast<__half2*>(&u);
}

// Fast ELU: native v_exp_f32 (abs threshold 0.765 makes expm1 precision moot).
__device__ __forceinline__ float elu_f(float x) {
    return x > 0.f ? x : (__expf(x) - 1.f);
}

// Prep: row_ptr lower-bound; pack edges as (col*128 byte-off, half2{v,v});
// convert x (f32) -> f16 table.
__global__ __launch_bounds__(256) void prep_kernel(const int* __restrict__ rows,
                                                   const int* __restrict__ cols,
                                                   const float* __restrict__ vals,
                                                   const float* __restrict__ x,
                                                   int* __restrict__ row_ptr,
                                                   int2* __restrict__ pairs,
                                                   unsigned short* __restrict__ xhf,
                                                   int do_pack) {
    const int i = blockIdx.x * blockDim.x + threadIdx.x;
    if (i <= N_NODES) {
        int lo = 0, hi = N_EDGES;
        while (lo < hi) {
            int mid = (lo + hi) >> 1;
            if (rows[mid] < i) lo = mid + 1; else hi = mid;
        }
        row_ptr[i] = lo;
    }
    if (do_pack && i < N_EDGES) {
        const float v = vals[i];
        pairs[i] = make_int2(cols[i] << 7, (int)pack2h(v, v));
    }
    if (i < XCHUNKS) {
        const float4 f0 = *reinterpret_cast<const float4*>(x + (size_t)i * 8);
        const float4 f1 = *reinterpret_cast<const float4*>(x + (size_t)i * 8 + 4);
        uint4 w;
        w.x = pack2h(f0.x, f0.y);
        w.y = pack2h(f0.z, f0.w);
        w.z = pack2h(f1.x, f1.y);
        w.w = pack2h(f1.z, f1.w);
        *reinterpret_cast<uint4*>(xhf + (size_t)i * 8) = w;
    }
}

// One 8-edge step for one row-group (16 lanes/row, 4 f16 features per lane).
// Same memory shape as the proven round-6 kernel; math is packed v_pk_fma_f16:
// 2 VALU per edge instead of 8 (no unpack, val pre-duplicated as half2).
template <bool PACKED, bool MASKED>
__device__ __forceinline__ void edge_step8(const char* __restrict__ hb,
                                           const int2* __restrict__ pairs,
                                           const int* __restrict__ cols,
                                           const float* __restrict__ vals,
                                           int e, int e1, int boff,
                                           __half2& A0, __half2& A1,
                                           __half2& B0, __half2& B1) {
    int off[8]; unsigned v2[8];
    #pragma unroll
    for (int k = 0; k < 8; ++k) {
        const int t = e + k;
        const int idx = MASKED ? (t < e1 ? t : e1 - 1) : t;
        if constexpr (PACKED) {
            const int2 p = pairs[idx];
            off[k] = p.x;
            v2[k]  = (unsigned)p.y;
        } else {
            off[k] = cols[idx] << 7;
            const float v = vals[idx];
            v2[k] = pack2h(v, v);
        }
        if (MASKED) v2[k] = (t < e1) ? v2[k] : 0u;
    }
    uint2 gg[8];
    #pragma unroll
    for (int k = 0; k < 8; ++k)
        gg[k] = *reinterpret_cast<const uint2*>(hb + (unsigned)(off[k] + boff));
    #pragma unroll
    for (int k = 0; k < 8; ++k) {
        const __half2 vv = as_h2(v2[k]);
        if (k & 1) {
            B0 = __hfma2(vv, as_h2(gg[k].x), B0);
            B1 = __hfma2(vv, as_h2(gg[k].y), B1);
        } else {
            A0 = __hfma2(vv, as_h2(gg[k].x), A0);
            A1 = __hfma2(vv, as_h2(gg[k].y), A1);
        }
    }
}

// SpMM layer over f16 h: 4 waves/block, 4 row-groups/wave (16 lanes per row,
// 4 f16 features per lane = 8B gather; 128B line per edge).
// !FUSE: h_out is f16 [N_NODES][64].  FUSE: h_out is f32 out = y @ W^T + b.
template <bool FUSE, bool PACKED>
__global__ __launch_bounds__(256) void gcn_layer(
    const unsigned short* __restrict__ h_in,  // f16 [N_NODES][64]
    const int2*  __restrict__ pairs,
    const int*   __restrict__ cols,
    const float* __restrict__ vals,
    const int*   __restrict__ row_ptr,
    const float* __restrict__ scalar_p,
    const float* __restrict__ W,        // [64,64] (FUSE only)
    const float* __restrict__ bvec,     // [64]    (FUSE only)
    void*        __restrict__ h_out)
{
    __shared__ float Wlds[FUSE ? 64 * 65 : 1];   // stride 65: conflict-free
    __shared__ float ylds[FUSE ? 4 * 4 * 68 : 1];// [wave][row][68 pad]

    const int lane = threadIdx.x & 63;
    const int wave = threadIdx.x >> 6;
    const int g    = lane >> 4;          // row-group 0..3
    const int f4   = lane & 15;          // 8B feature chunk index
    const int boff = f4 * 8;             // byte offset of this lane's chunk

    if constexpr (FUSE) {
        for (int i = threadIdx.x; i < 64 * 64; i += 256)
            Wlds[(i >> 6) * 65 + (i & 63)] = W[i];
        __syncthreads();
    }

    const int row = blockIdx.x * 16 + wave * 4 + g;
    const float s  = scalar_p[0];
    const int  e0  = row_ptr[row];
    const int  e1  = row_ptr[row + 1];
    const char* hb = (const char*)h_in;

    __half2 A0 = __floats2half2_rn(0.f, 0.f);
    __half2 A1 = A0, B0 = A0, B1 = A0;

    int e = e0;
    for (; e + 8 <= e1; e += 8)
        edge_step8<PACKED, false>(hb, pairs, cols, vals, e, e1, boff, A0, A1, B0, B1);
    if (e < e1)
        edge_step8<PACKED, true>(hb, pairs, cols, vals, e, e1, boff, A0, A1, B0, B1);

    // Convert to f32, combine A+B chains, scale + ELU.
    const float2 a0 = __half22float2(A0), a1 = __half22float2(A1);
    const float2 b0 = __half22float2(B0), b1 = __half22float2(B1);
    float4 acc;
    acc.x = elu_f((a0.x + b0.x) * s);
    acc.y = elu_f((a0.y + b0.y) * s);
    acc.z = elu_f((a1.x + b1.x) * s);
    acc.w = elu_f((a1.y + b1.y) * s);

    if constexpr (!FUSE) {
        uint2 wv;
        wv.x = pack2h(acc.x, acc.y);
        wv.y = pack2h(acc.z, acc.w);
        *reinterpret_cast<uint2*>((char*)h_out + (size_t)row * 128 + boff) = wv;
    } else {
        float* yw = ylds + wave * (4 * 68);
        *reinterpret_cast<float4*>(yw + g * 68 + f4 * 4) = acc;
        asm volatile("s_waitcnt lgkmcnt(0)" ::: "memory");  // same-wave ds ordering

        const int j = lane;
        const float bj = bvec[j];
        float o0 = bj, o1 = bj, o2 = bj, o3 = bj;
        #pragma unroll
        for (int d0 = 0; d0 < 16; ++d0) {
            const float* wr = Wlds + j * 65 + d0 * 4;  // stride-65: conflict-free
            const float w0 = wr[0], w1 = wr[1], w2 = wr[2], w3 = wr[3];
            const float4 y0 = *reinterpret_cast<const float4*>(yw + 0 * 68 + d0 * 4);
            const float4 y1 = *reinterpret_cast<const float4*>(yw + 1 * 68 + d0 * 4);
            const float4 y2 = *reinterpret_cast<const float4*>(yw + 2 * 68 + d0 * 4);
            const float4 y3 = *reinterpret_cast<const float4*>(yw + 3 * 68 + d0 * 4);
            o0 = fmaf(y0.x, w0, o0); o0 = fmaf(y0.y, w1, o0);
            o0 = fmaf(y0.z, w2, o0); o0 = fmaf(y0.w, w3, o0);
            o1 = fmaf(y1.x, w0, o1); o1 = fmaf(y1.y, w1, o1);
            o1 = fmaf(y1.z, w2, o1); o1 = fmaf(y1.w, w3, o1);
            o2 = fmaf(y2.x, w0, o2); o2 = fmaf(y2.y, w1, o2);
            o2 = fmaf(y2.z, w2, o2); o2 = fmaf(y2.w, w3, o2);
            o3 = fmaf(y3.x, w0, o3); o3 = fmaf(y3.y, w1, o3);
            o3 = fmaf(y3.z, w2, o3); o3 = fmaf(y3.w, w3, o3);
        }
        const size_t rbase = (size_t)(blockIdx.x * 16 + wave * 4) * D_FEAT;
        float* outp = (float*)h_out;
        outp[rbase + 0 * D_FEAT + j] = o0;
        outp[rbase + 1 * D_FEAT + j] = o1;
        outp[rbase + 2 * D_FEAT + j] = o2;
        outp[rbase + 3 * D_FEAT + j] = o3;
    }
}

extern "C" void kernel_launch(void* const* d_in, const int* in_sizes, int n_in,
                              void* d_out, int out_size, void* d_ws, size_t ws_size,
                              hipStream_t stream) {
    const float* x       = (const float*)d_in[0];
    const int*   rows    = (const int*)  d_in[1];
    const int*   cols    = (const int*)  d_in[2];
    const float* vals    = (const float*)d_in[3];
    const float* scalars = (const float*)d_in[4];
    const float* W       = (const float*)d_in[5];
    const float* b       = (const float*)d_in[6];
    float* out = (float*)d_out;

    // ws layout: row_ptr | xhf (f16) | h1 (f16) | (optional) packed pairs
    const size_t rp_b = (sizeof(int) * (N_NODES + 1) + 255) & ~size_t(255);
    const size_t xb_b = ((size_t)N_NODES * D_FEAT * 2 + 255) & ~size_t(255);
    const size_t pr_b = sizeof(int2) * (size_t)N_EDGES;

    int*            row_ptr = (int*)d_ws;
    unsigned short* xhf     = (unsigned short*)((char*)d_ws + rp_b);
    unsigned short* h1      = (unsigned short*)((char*)d_ws + rp_b + xb_b);
    const bool packed = ws_size >= rp_b + 2 * xb_b + pr_b;
    int2* pairs = packed ? (int2*)((char*)d_ws + rp_b + 2 * xb_b) : nullptr;

    prep_kernel<<<(N_EDGES + 255) / 256, 256, 0, stream>>>(
        rows, cols, vals, x, row_ptr, pairs, xhf, packed ? 1 : 0);

    if (packed) {
        gcn_layer<false, true><<<NBLK, 256, 0, stream>>>(
            xhf, pairs, cols, vals, row_ptr, scalars + 0, nullptr, nullptr, h1);
        gcn_layer<true, true><<<NBLK, 256, 0, stream>>>(
            h1, pairs, cols, vals, row_ptr, scalars + 1, W, b, out);
    } else {
        gcn_layer<false, false><<<NBLK, 256, 0, stream>>>(
            xhf, nullptr, cols, vals, row_ptr, scalars + 0, nullptr, nullptr, h1);
        gcn_layer<true, false><<<NBLK, 256, 0, stream>>>(
            h1, nullptr, cols, vals, row_ptr, scalars + 1, W, b, out);
    }
}